// Round 7
// baseline (40989.862 us; speedup 1.0000x reference)
//
#include <hip/hip_runtime.h>
#include <math.h>

typedef unsigned short u16;
typedef unsigned int   u32;

#define V_SZ   32000
#define E_SZ   512
#define H_SZ   1024
#define S_LEN  2048
#define T_LEN  2048
#define TEAM   32            // WGs in the XCD-local RNN team
#define ROWS_PW 32           // rows of Whh per team WG (H_SZ / TEAM)
#define NCAND  1024          // candidate WGs launched; non-winners exit
#define NTILE_V (V_SZ / 128) // 250 N-tiles in the scores GEMM

typedef __attribute__((ext_vector_type(8))) short bf16x8;
typedef __attribute__((ext_vector_type(4))) float f32x4;

typedef __attribute__((address_space(3))) void* lds_vp;
typedef const __attribute__((address_space(1))) void* gbl_vp;

__device__ __forceinline__ float bf2f(u16 u) { return __uint_as_float(((u32)u) << 16); }
__device__ __forceinline__ u16 f2bf(float f) {           // round-to-nearest-even
  u32 x = __float_as_uint(f);
  return (u16)((x + 0x7fffu + ((x >> 16) & 1u)) >> 16);
}
__device__ __forceinline__ bool f32_bad(float f) {
  return (__float_as_uint(f) & 0x7F800000u) == 0x7F800000u;
}
__device__ __forceinline__ bool bf_bad(u16 u) { return (u & 0x7F80u) == 0x7F80u; }

__device__ __forceinline__ bf16x8 cvt8(float4 a, float4 b) {
  bf16x8 r;
  r[0] = (short)f2bf(a.x); r[1] = (short)f2bf(a.y);
  r[2] = (short)f2bf(a.z); r[3] = (short)f2bf(a.w);
  r[4] = (short)f2bf(b.x); r[5] = (short)f2bf(b.y);
  r[6] = (short)f2bf(b.z); r[7] = (short)f2bf(b.w);
  return r;
}

// Fast-path poll: sc0 loads (bypass L1, read the XCD-local L2). Both loads issued
// before a single vmcnt(0). Callers interleave agent-scope loads every 32 iterations
// as a progress guarantee (R6 measured: agent-published data is ONLY seen by that
// fallback; this round fixes the publish side instead).
__device__ __forceinline__ void l2_load2(const u32* p0, const u32* p1, u32& a, u32& b) {
  asm volatile("global_load_dword %0, %2, off sc0\n\t"
               "global_load_dword %1, %3, off sc0\n\t"
               "s_waitcnt vmcnt(0)"
               : "=&v"(a), "=&v"(b) : "v"(p0), "v"(p1) : "memory");
}
// Publish: sc0 store DIRTIES THE LOCAL L2 (write-back, L1-bypass) -> visible to sc0
// polls on the same XCD at L2-hit latency. R6's agent-scope publish bypassed L2 to
// MALL and left the local L2 clean-stale, so sc0 polls never saw it (the measured
// 32-iteration detect quantization). The caller follows with an agent store to the
// same word so the MALL copy advances too (fallback path stays functional).
__device__ __forceinline__ void l2_store(u32* p, u32 v) {
  asm volatile("global_store_dword %0, %1, off sc0" :: "v"(p), "v"(v) : "memory");
}

// ---------------------------------------------------------------- tiny outputs (f32)
__global__ void sentinel_kernel(float* out) { out[0] = -400.0f; }
__global__ void diag_kernel(float* out, float code) { out[0] = code; }

// ---------------------------------------------------------------- init (f32 inputs)
__global__ __launch_bounds__(256) void init_kernel(
    const float* __restrict__ enc_bih, const float* __restrict__ enc_bhh,
    const float* __restrict__ dec_bih, const float* __restrict__ dec_bhh,
    float* biasE, float* biasD,
    u32* hsync, u32* team_ctl, float* loss_acc, float* prog)
{
  int i = blockIdx.x * blockDim.x + threadIdx.x;
  if (i < H_SZ) {
    biasE[i] = enc_bih[i] + enc_bhh[i];
    biasD[i] = dec_bih[i] + dec_bhh[i];
  }
  if (i < 2 * H_SZ)   // zero both ring-buffer slots (tags become invalid)
    __hip_atomic_store(hsync + i, 0u, __ATOMIC_RELAXED, __HIP_MEMORY_SCOPE_AGENT);
  if (i < 32)         // ctl: [0..7] cnt, [8] winner, [9] arrivals; +16 for decoder
    __hip_atomic_store(team_ctl + i, (i == 8 || i == 24) ? 0xFFFFFFFFu : 0u,
                       __ATOMIC_RELAXED, __HIP_MEMORY_SCOPE_AGENT);
  if (i == 0)    { loss_acc[0] = 0.f; prog[0] = 1.0f; }
  if (i >= 1 && i < 16) prog[i] = 0.f;
}

// ---------------------------------------------------------------- embedding gather (f32 -> bf16)
__global__ __launch_bounds__(256) void gather_kernel(
    const float* __restrict__ emb, const int* __restrict__ ids, u16* __restrict__ dst,
    float* prog, int pidx)
{
  const int row = blockIdx.x;
  const int id  = ids[row];
  const float2* s = (const float2*)(emb + (size_t)id * E_SZ);
  const float2 v = s[threadIdx.x];                 // 256 threads x 2 floats = 512
  const u32 pack = (u32)f2bf(v.x) | ((u32)f2bf(v.y) << 16);
  ((u32*)(dst + (size_t)row * E_SZ))[threadIdx.x] = pack;
  if (row == 0 && threadIdx.x == 0) prog[pidx] = 1.0f;
}

// ---------------------------------------------------------------- generic GEMM
// C[M,N] = A[M,K](lda,bf16) @ B[N,K](ldb)^T + bias[N]
// BF32=1: B is float32, staged via registers with f32->bf16 convert.
// MODE 1: store bf16 C;  MODE 2: per-(row, n-tile) logsumexp stats
template<int MODE, int BF32>
__global__ __launch_bounds__(256) void gemm_bt(
    const u16* __restrict__ A, int lda,
    const void* __restrict__ Bp, int ldb,
    const float* __restrict__ bias,
    u16* __restrict__ Cbf, int ldc,
    float* __restrict__ stats, int ntiles, int K,
    float* prog, int pidx)
{
  __shared__ __align__(16) u16 As[128 * 32];
  __shared__ __align__(16) u16 Bs[128 * 32];
  __shared__ float sst[2][128][2];

  const int tid  = threadIdx.x;
  const int wave = tid >> 6;
  const int lane = tid & 63;
  const int quad = lane >> 4;
  const int l16  = lane & 15;
  const int m0 = blockIdx.y * 128;
  const int n0 = blockIdx.x * 128;
  const int wm = (wave >> 1) * 64;
  const int wn = (wave & 1) * 64;

  f32x4 acc[4][4];
#pragma unroll
  for (int i = 0; i < 4; ++i)
#pragma unroll
    for (int j = 0; j < 4; ++j) acc[i][j] = (f32x4){0.f, 0.f, 0.f, 0.f};

  const int srow = lane >> 2;            // 0..15 row within 16x32 chunk
  const int scol = (lane & 3) * 8;       // 0,8,16,24
  const int c0   = wave * 2;             // this wave stages chunks c0, c0+1
  const u16* ga0 = A + (size_t)(m0 + (c0 + 0) * 16 + srow) * lda + scol;
  const u16* ga1 = A + (size_t)(m0 + (c0 + 1) * 16 + srow) * lda + scol;
  const u16*   B16 = (const u16*)Bp;
  const float* B32 = (const float*)Bp;
  const u16* gb0 = B16 + (size_t)(n0 + (c0 + 0) * 16 + srow) * ldb + scol;
  const u16* gb1 = B16 + (size_t)(n0 + (c0 + 1) * 16 + srow) * ldb + scol;
  const float* fb0 = B32 + (size_t)(n0 + (c0 + 0) * 16 + srow) * ldb + scol;
  const float* fb1 = B32 + (size_t)(n0 + (c0 + 1) * 16 + srow) * ldb + scol;

  for (int k0 = 0; k0 < K; k0 += 32) {
    __builtin_amdgcn_global_load_lds((gbl_vp)(ga0 + k0), (lds_vp)(&As[(c0 + 0) * 512]), 16, 0, 0);
    __builtin_amdgcn_global_load_lds((gbl_vp)(ga1 + k0), (lds_vp)(&As[(c0 + 1) * 512]), 16, 0, 0);
    if (BF32) {
      const float* p0 = fb0 + k0;
      const float* p1 = fb1 + k0;
      const float4 a0 = *(const float4*)p0, a1 = *(const float4*)(p0 + 4);
      const float4 b0 = *(const float4*)p1, b1 = *(const float4*)(p1 + 4);
      *(bf16x8*)&Bs[(c0 + 0) * 512 + lane * 8] = cvt8(a0, a1);
      *(bf16x8*)&Bs[(c0 + 1) * 512 + lane * 8] = cvt8(b0, b1);
    } else {
      __builtin_amdgcn_global_load_lds((gbl_vp)(gb0 + k0), (lds_vp)(&Bs[(c0 + 0) * 512]), 16, 0, 0);
      __builtin_amdgcn_global_load_lds((gbl_vp)(gb1 + k0), (lds_vp)(&Bs[(c0 + 1) * 512]), 16, 0, 0);
    }
    __syncthreads();

    bf16x8 af[4], bg[4];
#pragma unroll
    for (int i = 0; i < 4; ++i) {
      af[i] = *(const bf16x8*)&As[(wm + i * 16 + l16) * 32 + quad * 8];
      bg[i] = *(const bf16x8*)&Bs[(wn + i * 16 + l16) * 32 + quad * 8];
    }
#pragma unroll
    for (int mi = 0; mi < 4; ++mi)
#pragma unroll
      for (int ni = 0; ni < 4; ++ni)
        acc[mi][ni] = __builtin_amdgcn_mfma_f32_16x16x32_bf16(af[mi], bg[ni], acc[mi][ni], 0, 0, 0);
    __syncthreads();
  }

  if (MODE == 2) {
#pragma unroll
    for (int mi = 0; mi < 4; ++mi) {
#pragma unroll
      for (int rr = 0; rr < 4; ++rr) {
        float v[4];
        float vmax = -1e30f;
#pragma unroll
        for (int ni = 0; ni < 4; ++ni) {
          const int col = n0 + wn + ni * 16 + l16;
          v[ni] = acc[mi][ni][rr] + (bias ? bias[col] : 0.f);
          vmax = fmaxf(vmax, v[ni]);
        }
        for (int d = 1; d < 16; d <<= 1) vmax = fmaxf(vmax, __shfl_xor(vmax, d, 64));
        float vs = 0.f;
#pragma unroll
        for (int ni = 0; ni < 4; ++ni) vs += expf(v[ni] - vmax);
        for (int d = 1; d < 16; d <<= 1) vs += __shfl_xor(vs, d, 64);
        if (l16 == 0) {
          const int lr = wm + mi * 16 + quad * 4 + rr;
          sst[wave & 1][lr][0] = vmax;
          sst[wave & 1][lr][1] = vs;
        }
      }
    }
    __syncthreads();
    if (tid < 128) {
      const float ma = sst[0][tid][0], sa = sst[0][tid][1];
      const float mb = sst[1][tid][0], sb = sst[1][tid][1];
      const float M = fmaxf(ma, mb);
      const float S = sa * expf(ma - M) + sb * expf(mb - M);
      const size_t row = (size_t)(m0 + tid);
      stats[(row * ntiles + blockIdx.x) * 2 + 0] = M;
      stats[(row * ntiles + blockIdx.x) * 2 + 1] = S;
    }
  } else {
#pragma unroll
    for (int mi = 0; mi < 4; ++mi)
#pragma unroll
      for (int ni = 0; ni < 4; ++ni) {
        const int col = n0 + wn + ni * 16 + l16;
        const float bb = bias ? bias[col] : 0.f;
#pragma unroll
        for (int rr = 0; rr < 4; ++rr) {
          const int row = m0 + wm + mi * 16 + quad * 4 + rr;
          Cbf[(size_t)row * ldc + col] = f2bf(acc[mi][ni][rr] + bb);
        }
      }
  }
  if (prog && blockIdx.x == 0 && blockIdx.y == 0 && tid == 0) prog[pidx] = 1.0f;
}

// ---------------------------------------------------------------- persistent RNN, XCD-local team
// h_t = tanh(pre[t] + Whh @ h_{t-1}).
//
// TEAM SELECTION (hang-proof, R6-verified): NCAND WGs; per-XCD ticket via XCC_ID;
// winner = first XCD to 32 tickets, or argmax declared by any WG arriving >=512th.
//
// SYNC: tagged words u32=(tag<<16)|bf16(h), 2-slot ring.
//   PUBLISH: sc0 store (dirties the team's own L2 -> sc0-poll-visible at L2 latency)
//            followed by an agent store of the same word (advances the MALL copy so
//            the fallback path also sees progress; same-address program order).
//   POLL: sc0 loads; every 32nd iteration an agent-scope load (progress guarantee).
//   R6 measured the failure of agent-only publish: sc0 polls hit a clean-stale L2
//   line forever, detect quantized to the fallback period (7.3us/step). This round
//   puts the data IN the L2 the polls read.
// Ring-depth-2 safety: each WG's publish is barrier-ordered after its poll, so a WG
// at step t proves all WGs finished reading slot t&1 (their step t-1 poll) first.
//
// COMPUTE: Whh rows in REGISTERS (64 f32/thread, loaded once); h staged f32 in an
// 8KB LDS double buffer; 4 conflict-free ds_read_b128 + 64 v_fmac + 24 shuffles.
__global__ __launch_bounds__(512) void rnn_kernel(
    const float* __restrict__ Whh, const u16* __restrict__ pre,
    u16* __restrict__ hist, int ldh, const u16* __restrict__ h0,
    u16* __restrict__ outT,
    u32* __restrict__ hsync, u32* __restrict__ ctl,
    int tagbase, int T, float* prog, int pidx)
{
  __shared__ float hbuf[2][H_SZ];      // 8 KB double-buffered h (f32)
  __shared__ int s_slot;

  const int tid  = threadIdx.x;        // 0..511
  const int wv   = tid >> 6;           // wave 0..7
  const int lane = tid & 63;

  u32 xcd;
  asm volatile("s_getreg_b32 %0, hwreg(HW_REG_XCC_ID)" : "=s"(xcd));
  xcd &= 7u;

  if (tid == 0) {
    const u32 t = atomicAdd(&ctl[xcd], 1u);                  // per-XCD ticket
    if (t == TEAM - 1) atomicCAS(&ctl[8], 0xFFFFFFFFu, xcd); // trigger (a)
    const u32 g = atomicAdd(&ctl[9], 1u);                    // global arrivals
    if (g >= 511u &&
        __hip_atomic_load(&ctl[8], __ATOMIC_RELAXED, __HIP_MEMORY_SCOPE_AGENT)
          == 0xFFFFFFFFu) {                                  // trigger (b): argmax
      u32 best = 0, bc = 0;
      for (u32 i = 0; i < 8; ++i) {
        const u32 c = __hip_atomic_load(&ctl[i], __ATOMIC_RELAXED,
                                        __HIP_MEMORY_SCOPE_AGENT);
        if (c > bc) { bc = c; best = i; }
      }
      atomicCAS(&ctl[8], 0xFFFFFFFFu, best);
    }
    u32 w;
    while ((w = __hip_atomic_load(&ctl[8], __ATOMIC_RELAXED,
                                  __HIP_MEMORY_SCOPE_AGENT)) == 0xFFFFFFFFu)
      __builtin_amdgcn_s_sleep(2);
    s_slot = (w == xcd && t < TEAM) ? (int)t : -1;
  }
  __syncthreads();
  const int slot = s_slot;
  if (slot < 0) return;                // not on the winning die / surplus -> exit

  // ---- one-time: this wave's 4 Whh rows into registers (f32)
  const int rbase = slot * ROWS_PW + wv * 4;
  float wreg[4][16];
#pragma unroll
  for (int r = 0; r < 4; ++r) {
    const float* wrow = Whh + (size_t)(rbase + r) * H_SZ;
#pragma unroll
    for (int j = 0; j < 4; ++j) {
      const float4 v = *(const float4*)(wrow + j * 256 + lane * 4);
      wreg[r][j * 4 + 0] = v.x; wreg[r][j * 4 + 1] = v.y;
      wreg[r][j * 4 + 2] = v.z; wreg[r][j * 4 + 3] = v.w;
    }
  }

  // step-0 h into buffer 0 (f32)
  hbuf[0][tid]       = h0 ? bf2f(h0[tid])       : 0.f;
  hbuf[0][tid + 512] = h0 ? bf2f(h0[tid + 512]) : 0.f;

  const bool own0 = ((tid >> 5) == slot);          // word tid produced by this WG
  const bool own1 = (((tid + 512) >> 5) == slot);  // word tid+512 produced by this WG

  for (int t = 0; t < T; ++t) {
    float* hb = hbuf[t & 1];

    float pv = 0.f;                    // pre for this wave's 4 rows; load early
    if (lane < 4) pv = bf2f(pre[(size_t)t * H_SZ + rbase + lane]);

    if (t > 0) {
      const u32 want = (u32)(tagbase + t);          // tag written at step t-1
      u32* hs = hsync + (((t - 1) & 1) << 10);
      u32 got = (own0 ? 1u : 0u) | (own1 ? 2u : 0u);
      u32 spin = 0;
      while (got != 3u) {
        u32 x0, x1;
        if (((++spin) & 31u) == 0u) {               // progress-guarantee fallback
          x0 = __hip_atomic_load(hs + tid,       __ATOMIC_RELAXED, __HIP_MEMORY_SCOPE_AGENT);
          x1 = __hip_atomic_load(hs + tid + 512, __ATOMIC_RELAXED, __HIP_MEMORY_SCOPE_AGENT);
        } else {
          l2_load2(hs + tid, hs + tid + 512, x0, x1);
        }
        if (!(got & 1u) && (x0 >> 16) == want) { hb[tid]       = bf2f((u16)x0); got |= 1u; }
        if (!(got & 2u) && (x1 >> 16) == want) { hb[tid + 512] = bf2f((u16)x1); got |= 2u; }
      }
    }
    __syncthreads();                   // single barrier per step

    // matvec: lane's 16 h values (4 conflict-free float4 reads), 4 rows from registers
    float hk[16];
#pragma unroll
    for (int j = 0; j < 4; ++j) {
      const float4 v = *(const float4*)&hb[j * 256 + lane * 4];
      hk[j * 4 + 0] = v.x; hk[j * 4 + 1] = v.y; hk[j * 4 + 2] = v.z; hk[j * 4 + 3] = v.w;
    }
    float a0 = 0.f, a1 = 0.f, a2 = 0.f, a3 = 0.f;
#pragma unroll
    for (int k = 0; k < 16; ++k) {
      const float h = hk[k];
      a0 += wreg[0][k] * h;
      a1 += wreg[1][k] * h;
      a2 += wreg[2][k] * h;
      a3 += wreg[3][k] * h;
    }
#pragma unroll
    for (int d = 1; d < 64; d <<= 1) {
      a0 += __shfl_xor(a0, d, 64);
      a1 += __shfl_xor(a1, d, 64);
      a2 += __shfl_xor(a2, d, 64);
      a3 += __shfl_xor(a3, d, 64);
    }

    if (lane < 4) {                    // lane r publishes row rbase+r
      const float s = (lane == 0) ? a0 : (lane == 1) ? a1 : (lane == 2) ? a2 : a3;
      const float hn = tanhf(pv + s);
      const u16 hv16 = f2bf(hn);
      const int gr = rbase + lane;
      const u32 word = ((u32)(tagbase + t + 1) << 16) | (u32)hv16;
      u32* dst = hsync + ((t & 1) << 10) + gr;
      l2_store(dst, word);             // 1) dirty the local L2 (fast path, critical)
      __hip_atomic_store(dst, word,    // 2) advance the MALL copy (fallback path)
                         __ATOMIC_RELAXED, __HIP_MEMORY_SCOPE_AGENT);
      hbuf[(t + 1) & 1][gr] = bf2f(hv16);             // own fast path (bf16-rounded)
      hist[(size_t)t * ldh + gr] = hv16;
      if (outT) outT[(size_t)gr * S_LEN + t] = hv16;
    }
    // no trailing barrier: hbuf double-buffered; per-step barrier bounds wave skew
  }
  if (slot == 0 && tid == 0) prog[pidx] = 1.0f;
}

// ---------------------------------------------------------------- attention softmax (bf16, in-place)
__global__ __launch_bounds__(256) void softmax_kernel(
    u16* __restrict__ aff, float* prog, int pidx)
{
  const int row = blockIdx.x;
  const int tid = threadIdx.x;
  u16* a = aff + (size_t)row * S_LEN;
  __shared__ float red[256];

  float m = -1e30f;
  for (int j = tid; j < S_LEN; j += 256) m = fmaxf(m, bf2f(a[j]));
  red[tid] = m; __syncthreads();
  for (int s = 128; s > 0; s >>= 1) { if (tid < s) red[tid] = fmaxf(red[tid], red[tid + s]); __syncthreads(); }
  const float M = red[0];
  __syncthreads();

  float sum = 0.f;
  for (int j = tid; j < S_LEN; j += 256) sum += expf(bf2f(a[j]) - M);
  red[tid] = sum; __syncthreads();
  for (int s = 128; s > 0; s >>= 1) { if (tid < s) red[tid] += red[tid + s]; __syncthreads(); }
  const float inv = 1.f / red[0];

  for (int j = tid; j < S_LEN; j += 256) {
    const float e = expf(bf2f(a[j]) - M) * inv;   // read then overwrite, same thread/index
    a[j] = f2bf(e);
  }
  if (row == 0 && tid == 0) prog[pidx] = 1.0f;
}

// ---------------------------------------------------------------- loss (out_W/out_b are f32)
__global__ __launch_bounds__(256) void loss_kernel(
    const u16* __restrict__ proj_bf, const float* __restrict__ outW,
    const float* __restrict__ outb, const int* __restrict__ target,
    const float* __restrict__ stats, int ntiles, float* loss_acc,
    float* prog, int pidx)
{
  const int t   = blockIdx.x;      // 0..T-2
  const int tid = threadIdx.x;
  const int c   = target[t + 1];
  __shared__ float s1[256], s2[256];

  float p = 0.f;
  const u16*   pr = proj_bf + (size_t)t * H_SZ;
  const float* wr = outW + (size_t)c * H_SZ;
  for (int j = tid; j < H_SZ; j += 256) p += bf2f(pr[j]) * f2bf(wr[j]) * 0.f + bf2f(pr[j]) * bf2f(f2bf(wr[j]));
  s1[tid] = p; __syncthreads();
  for (int s = 128; s > 0; s >>= 1) { if (tid < s) s1[tid] += s1[tid + s]; __syncthreads(); }
  const float dotv = s1[0] + outb[c];

  const float* st = stats + (size_t)t * ntiles * 2;
  float mi = -1e30f, si = 0.f;
  if (tid < ntiles) { mi = st[tid * 2]; si = st[tid * 2 + 1]; }
  s2[tid] = mi; __syncthreads();
  for (int s = 128; s > 0; s >>= 1) { if (tid < s) s2[tid] = fmaxf(s2[tid], s2[tid + s]); __syncthreads(); }
  const float M = s2[0];
  const float e = (tid < ntiles) ? si * expf(mi - M) : 0.f;
  __syncthreads();
  s1[tid] = e; __syncthreads();
  for (int s = 128; s > 0; s >>= 1) { if (tid < s) s1[tid] += s1[tid + s]; __syncthreads(); }

  if (tid == 0) {
    atomicAdd(loss_acc, (M + logf(s1[0])) - dotv);
    if (t == 0) prog[pidx] = 1.0f;
  }
}

// ---------------------------------------------------------------- finalize + telemetry (f32 out)
// out codes: loss (success) | -(100+i) kernel i never ran | -(200+10s) first bad stage
//            -300 loss non-finite, no bad stage found | -400 sentinel (finalize never ran)
//            -(1000+wsMB) workspace too small
__global__ void finalize_kernel(
    const float* loss_acc, const float* prog,
    const float* biasE, const float* biasD,
    const u16* enc_out, const u16* cat, const u16* proj_bf, const float* stats,
    float* out)
{
  for (int i = 0; i < 13; ++i)
    if (prog[i] != 1.0f) { out[0] = -(100.0f + i); return; }

  const float loss = loss_acc[0];
  if (!f32_bad(loss)) { out[0] = loss; return; }

  int s = -1;
  for (int i = 0; i < 37 && s < 0; ++i)
    if (f32_bad(biasE[(i * 97) % H_SZ]) || f32_bad(biasD[(i * 97) % H_SZ])) s = 0;
  for (int i = 0; i < 37 && s < 0; ++i)
    if (bf_bad(enc_out[((size_t)i * 131071u) % (2048u * 1024u)])) s = 2;
  for (int i = 0; i < 37 && s < 0; ++i)
    if (bf_bad(cat[(((size_t)(i * 557) % 2048) * 2048) + (i * 97) % 1024])) s = 3;
  for (int i = 0; i < 37 && s < 0; ++i)
    if (bf_bad(cat[(((size_t)(i * 557) % 2048) * 2048) + 1024 + (i * 97) % 1024])) s = 5;
  for (int i = 0; i < 37 && s < 0; ++i)
    if (bf_bad(proj_bf[((size_t)i * 131071u) % (2048u * 1024u)])) s = 6;
  for (int i = 0; i < 37 && s < 0; ++i)
    if (f32_bad(stats[((size_t)i * 99991u) % (2048u * 500u)])) s = 7;
  out[0] = (s < 0) ? -300.0f : -(200.0f + 10.0f * s);
}

// ---------------------------------------------------------------- launcher
// Workspace plan (~24.2 MB), bulk tensors bf16:
//   [ 0, 2)MB src_emb   } -> after pre-GEMMs: enc_outT [H][S] (4MB)
//   [ 2, 4)MB tgt_emb   }    -> after ctx GEMM: proj_bf (4MB)
//   [ 4, 8)MB enc_pre   } -> after RNNs: aff [T][S] bf16 (8MB)
//   [ 8,12)MB dec_pre   }    -> after ctx GEMM: stats f32 (4.1MB)
//   [12,16)MB enc_out [S][H] (= enc hist; live to the end)
//   [16,24)MB cat [T][2H]    (dec half doubles as dec hist; live to the end)
//   [24MB,+) tail: biasE/D, loss_acc, prog, hsync ring (8KB), team_ctl (128B)
extern "C" void kernel_launch(void* const* d_in, const int* in_sizes, int n_in,
                              void* d_out, int out_size, void* d_ws, size_t ws_size,
                              hipStream_t stream)
{
  (void)in_sizes; (void)n_in; (void)out_size;

  const int*   src     = (const int*)d_in[0];
  const int*   tgt     = (const int*)d_in[1];
  const float* emb     = (const float*)d_in[2];
  const float* enc_Wih = (const float*)d_in[3];
  const float* enc_bih = (const float*)d_in[4];
  const float* enc_Whh = (const float*)d_in[5];
  const float* enc_bhh = (const float*)d_in[6];
  const float* dec_Wih = (const float*)d_in[7];
  const float* dec_bih = (const float*)d_in[8];
  const float* dec_Whh = (const float*)d_in[9];
  const float* dec_bhh = (const float*)d_in[10];
  const float* proj_W  = (const float*)d_in[11];
  const float* proj_b  = (const float*)d_in[12];
  const float* out_W   = (const float*)d_in[13];
  const float* out_b   = (const float*)d_in[14];

  char* wsb = (char*)d_ws;
  const size_t MB = (size_t)1 << 20;
  u16*   src_emb  = (u16*)(wsb + 0);
  u16*   tgt_emb  = (u16*)(wsb + 2 * MB);
  u16*   enc_outT = (u16*)(wsb + 0);              // alias: embeddings dead after pre-GEMMs
  u16*   proj_bf  = (u16*)(wsb + 0);              // alias: enc_outT dead after ctx GEMM
  u16*   enc_pre  = (u16*)(wsb + 4 * MB);
  u16*   dec_pre  = (u16*)(wsb + 8 * MB);
  u16*   aff      = (u16*)(wsb + 4 * MB);         // alias: pre dead after RNNs; softmax in place
  float* stats    = (float*)(wsb + 4 * MB);       // alias: aff dead after ctx GEMM
  u16*   enc_out  = (u16*)(wsb + 12 * MB);        // enc hist [S][H]
  u16*   cat      = (u16*)(wsb + 16 * MB);        // [T][2H]; dec half = dec hist
  char*  tail     = wsb + 24 * MB;
  float* biasE    = (float*)tail;
  float* biasD    = biasE + H_SZ;
  float* loss_acc = biasD + H_SZ;
  float* prog     = loss_acc + 64;
  u32*   hsync    = (u32*)(prog + 64);            // 2-slot ring: 2*1024 u32 = 8KB
  u32*   team_ctl = hsync + 2 * H_SZ;             // [0..9] enc, [16..25] dec
  const size_t need = 24 * MB + 64 * 1024;

  if (ws_size < need) {   // telemetry: out = -(1000 + ws_MB)
    diag_kernel<<<1, 1, 0, stream>>>((float*)d_out, -(1000.0f + (float)(ws_size / MB)));
    return;
  }

  sentinel_kernel<<<1, 1, 0, stream>>>((float*)d_out);

  init_kernel<<<S_LEN / 256, 256, 0, stream>>>(enc_bih, enc_bhh, dec_bih, dec_bhh,
      biasE, biasD, hsync, team_ctl, loss_acc, prog);

  gather_kernel<<<S_LEN, 256, 0, stream>>>(emb, src, src_emb, prog, 1);
  gather_kernel<<<T_LEN, 256, 0, stream>>>(emb, tgt, tgt_emb, prog, 2);

  // pre-activations: x @ Wih^T + (bih + bhh)  (bf16 out; Wih staged f32->bf16)
  gemm_bt<1, 1><<<dim3(H_SZ / 128, S_LEN / 128), 256, 0, stream>>>(
      src_emb, E_SZ, enc_Wih, E_SZ, biasE, enc_pre, H_SZ, nullptr, 0, E_SZ, prog, 3);
  gemm_bt<1, 1><<<dim3(H_SZ / 128, T_LEN / 128), 256, 0, stream>>>(
      tgt_emb, E_SZ, dec_Wih, E_SZ, biasD, dec_pre, H_SZ, nullptr, 0, E_SZ, prog, 4);

  // recurrences: XCD-local persistent team, L2-resident tagged-word sync
  rnn_kernel<<<NCAND, 512, 0, stream>>>(enc_Whh, enc_pre, enc_out, H_SZ, nullptr,
      enc_outT, hsync, team_ctl, 0, S_LEN, prog, 5);
  rnn_kernel<<<NCAND, 512, 0, stream>>>(dec_Whh, dec_pre, cat, 2 * H_SZ,
      enc_out + (size_t)(S_LEN - 1) * H_SZ, nullptr, hsync, team_ctl + 16, S_LEN, T_LEN, prog, 6);

  // aff = dec_out @ enc_out^T  (both bf16 ws tensors)
  gemm_bt<1, 0><<<dim3(S_LEN / 128, T_LEN / 128), 256, 0, stream>>>(
      cat, 2 * H_SZ, enc_out, H_SZ, nullptr, aff, S_LEN, nullptr, 0, H_SZ, prog, 7);
  softmax_kernel<<<T_LEN, 256, 0, stream>>>(aff, prog, 8);
  // ctx = attn @ enc_out -> cat[:,H:]   (B = enc_outT bf16)
  gemm_bt<1, 0><<<dim3(H_SZ / 128, T_LEN / 128), 256, 0, stream>>>(
      aff, S_LEN, enc_outT, S_LEN, nullptr, cat + H_SZ, 2 * H_SZ, nullptr, 0, S_LEN, prog, 9);
  // proj = cat @ proj_W^T + proj_b   (proj_W f32; overwrites dead enc_outT)
  gemm_bt<1, 1><<<dim3(H_SZ / 128, T_LEN / 128), 256, 0, stream>>>(
      cat, 2 * H_SZ, proj_W, 2 * H_SZ, proj_b, proj_bf, H_SZ, nullptr, 0, 2 * H_SZ, prog, 10);
  // scores = proj @ out_W^T + out_b -> per-tile logsumexp stats (out_W f32; overwrites dead aff)
  gemm_bt<2, 1><<<dim3(NTILE_V, T_LEN / 128), 256, 0, stream>>>(
      proj_bf, H_SZ, out_W, H_SZ, out_b, nullptr, 0, stats, NTILE_V, H_SZ, prog, 11);

  loss_kernel<<<T_LEN - 1, 256, 0, stream>>>(proj_bf, out_W, out_b, tgt, stats,
      NTILE_V, loss_acc, prog, 12);

  finalize_kernel<<<1, 1, 0, stream>>>(loss_acc, prog, biasE, biasD,
      enc_out, cat, proj_bf, stats, (float*)d_out);
}

// Round 8
// 10842.143 us; speedup vs baseline: 3.7806x; 3.7806x over previous
//
#include <hip/hip_runtime.h>
#include <math.h>

typedef unsigned short u16;
typedef unsigned int   u32;

#define V_SZ   32000
#define E_SZ   512
#define H_SZ   1024
#define S_LEN  2048
#define T_LEN  2048
#define G_RNN  64            // persistent workgroups in RNN kernel
#define RPW    16            // rows of Whh per workgroup (H_SZ / G_RNN)
#define WPAD   1032          // padded LDS row stride (elems)
#define NTILE_V (V_SZ / 128) // 250 N-tiles in the scores GEMM

typedef __attribute__((ext_vector_type(8))) short bf16x8;
typedef __attribute__((ext_vector_type(4))) float f32x4;
typedef __attribute__((ext_vector_type(4))) unsigned int u32x4;

typedef __attribute__((address_space(3))) void* lds_vp;
typedef const __attribute__((address_space(1))) void* gbl_vp;

__device__ __forceinline__ float bf2f(u16 u) { return __uint_as_float(((u32)u) << 16); }
__device__ __forceinline__ u16 f2bf(float f) {           // round-to-nearest-even
  u32 x = __float_as_uint(f);
  return (u16)((x + 0x7fffu + ((x >> 16) & 1u)) >> 16);
}
__device__ __forceinline__ bool f32_bad(float f) {
  return (__float_as_uint(f) & 0x7F800000u) == 0x7F800000u;
}
__device__ __forceinline__ bool bf_bad(u16 u) { return (u & 0x7F80u) == 0x7F80u; }

__device__ __forceinline__ bf16x8 cvt8(float4 a, float4 b) {
  bf16x8 r;
  r[0] = (short)f2bf(a.x); r[1] = (short)f2bf(a.y);
  r[2] = (short)f2bf(a.z); r[3] = (short)f2bf(a.w);
  r[4] = (short)f2bf(b.x); r[5] = (short)f2bf(b.y);
  r[6] = (short)f2bf(b.z); r[7] = (short)f2bf(b.w);
  return r;
}

// ---------------------------------------------------------------- tiny outputs (f32)
__global__ void sentinel_kernel(float* out) { out[0] = -400.0f; }
__global__ void diag_kernel(float* out, float code) { out[0] = code; }

// ---------------------------------------------------------------- init (f32 inputs)
__global__ __launch_bounds__(256) void init_kernel(
    const float* __restrict__ enc_bih, const float* __restrict__ enc_bhh,
    const float* __restrict__ dec_bih, const float* __restrict__ dec_bhh,
    float* biasE, float* biasD,
    u32* hsync, float* loss_acc, float* prog)
{
  int i = blockIdx.x * blockDim.x + threadIdx.x;
  if (i < H_SZ) {
    biasE[i] = enc_bih[i] + enc_bhh[i];
    biasD[i] = dec_bih[i] + dec_bhh[i];
  }
  if (i < 2 * H_SZ)   // zero both ring-buffer slots (tags become invalid)
    __hip_atomic_store(hsync + i, 0u, __ATOMIC_RELAXED, __HIP_MEMORY_SCOPE_AGENT);
  if (i == 0)    { loss_acc[0] = 0.f; prog[0] = 1.0f; }
  if (i >= 1 && i < 16) prog[i] = 0.f;
}

// ---------------------------------------------------------------- embedding gather (f32 -> bf16)
__global__ __launch_bounds__(256) void gather_kernel(
    const float* __restrict__ emb, const int* __restrict__ ids, u16* __restrict__ dst,
    float* prog, int pidx)
{
  const int row = blockIdx.x;
  const int id  = ids[row];
  const float2* s = (const float2*)(emb + (size_t)id * E_SZ);
  const float2 v = s[threadIdx.x];                 // 256 threads x 2 floats = 512
  const u32 pack = (u32)f2bf(v.x) | ((u32)f2bf(v.y) << 16);
  ((u32*)(dst + (size_t)row * E_SZ))[threadIdx.x] = pack;
  if (row == 0 && threadIdx.x == 0) prog[pidx] = 1.0f;
}

// ---------------------------------------------------------------- generic GEMM
// C[M,N] = A[M,K](lda,bf16) @ B[N,K](ldb)^T + bias[N]
// BF32=1: B is float32, staged via registers with f32->bf16 convert.
// MODE 1: store bf16 C;  MODE 2: per-(row, n-tile) logsumexp stats
template<int MODE, int BF32>
__global__ __launch_bounds__(256) void gemm_bt(
    const u16* __restrict__ A, int lda,
    const void* __restrict__ Bp, int ldb,
    const float* __restrict__ bias,
    u16* __restrict__ Cbf, int ldc,
    float* __restrict__ stats, int ntiles, int K,
    float* prog, int pidx)
{
  __shared__ __align__(16) u16 As[128 * 32];
  __shared__ __align__(16) u16 Bs[128 * 32];
  __shared__ float sst[2][128][2];

  const int tid  = threadIdx.x;
  const int wave = tid >> 6;
  const int lane = tid & 63;
  const int quad = lane >> 4;
  const int l16  = lane & 15;
  const int m0 = blockIdx.y * 128;
  const int n0 = blockIdx.x * 128;
  const int wm = (wave >> 1) * 64;
  const int wn = (wave & 1) * 64;

  f32x4 acc[4][4];
#pragma unroll
  for (int i = 0; i < 4; ++i)
#pragma unroll
    for (int j = 0; j < 4; ++j) acc[i][j] = (f32x4){0.f, 0.f, 0.f, 0.f};

  const int srow = lane >> 2;            // 0..15 row within 16x32 chunk
  const int scol = (lane & 3) * 8;       // 0,8,16,24
  const int c0   = wave * 2;             // this wave stages chunks c0, c0+1
  const u16* ga0 = A + (size_t)(m0 + (c0 + 0) * 16 + srow) * lda + scol;
  const u16* ga1 = A + (size_t)(m0 + (c0 + 1) * 16 + srow) * lda + scol;
  const u16*   B16 = (const u16*)Bp;
  const float* B32 = (const float*)Bp;
  const u16* gb0 = B16 + (size_t)(n0 + (c0 + 0) * 16 + srow) * ldb + scol;
  const u16* gb1 = B16 + (size_t)(n0 + (c0 + 1) * 16 + srow) * ldb + scol;
  const float* fb0 = B32 + (size_t)(n0 + (c0 + 0) * 16 + srow) * ldb + scol;
  const float* fb1 = B32 + (size_t)(n0 + (c0 + 1) * 16 + srow) * ldb + scol;

  for (int k0 = 0; k0 < K; k0 += 32) {
    __builtin_amdgcn_global_load_lds((gbl_vp)(ga0 + k0), (lds_vp)(&As[(c0 + 0) * 512]), 16, 0, 0);
    __builtin_amdgcn_global_load_lds((gbl_vp)(ga1 + k0), (lds_vp)(&As[(c0 + 1) * 512]), 16, 0, 0);
    if (BF32) {
      const float* p0 = fb0 + k0;
      const float* p1 = fb1 + k0;
      const float4 a0 = *(const float4*)p0, a1 = *(const float4*)(p0 + 4);
      const float4 b0 = *(const float4*)p1, b1 = *(const float4*)(p1 + 4);
      *(bf16x8*)&Bs[(c0 + 0) * 512 + lane * 8] = cvt8(a0, a1);
      *(bf16x8*)&Bs[(c0 + 1) * 512 + lane * 8] = cvt8(b0, b1);
    } else {
      __builtin_amdgcn_global_load_lds((gbl_vp)(gb0 + k0), (lds_vp)(&Bs[(c0 + 0) * 512]), 16, 0, 0);
      __builtin_amdgcn_global_load_lds((gbl_vp)(gb1 + k0), (lds_vp)(&Bs[(c0 + 1) * 512]), 16, 0, 0);
    }
    __syncthreads();

    bf16x8 af[4], bg[4];
#pragma unroll
    for (int i = 0; i < 4; ++i) {
      af[i] = *(const bf16x8*)&As[(wm + i * 16 + l16) * 32 + quad * 8];
      bg[i] = *(const bf16x8*)&Bs[(wn + i * 16 + l16) * 32 + quad * 8];
    }
#pragma unroll
    for (int mi = 0; mi < 4; ++mi)
#pragma unroll
      for (int ni = 0; ni < 4; ++ni)
        acc[mi][ni] = __builtin_amdgcn_mfma_f32_16x16x32_bf16(af[mi], bg[ni], acc[mi][ni], 0, 0, 0);
    __syncthreads();
  }

  if (MODE == 2) {
#pragma unroll
    for (int mi = 0; mi < 4; ++mi) {
#pragma unroll
      for (int rr = 0; rr < 4; ++rr) {
        float v[4];
        float vmax = -1e30f;
#pragma unroll
        for (int ni = 0; ni < 4; ++ni) {
          const int col = n0 + wn + ni * 16 + l16;
          v[ni] = acc[mi][ni][rr] + (bias ? bias[col] : 0.f);
          vmax = fmaxf(vmax, v[ni]);
        }
        for (int d = 1; d < 16; d <<= 1) vmax = fmaxf(vmax, __shfl_xor(vmax, d, 64));
        float vs = 0.f;
#pragma unroll
        for (int ni = 0; ni < 4; ++ni) vs += expf(v[ni] - vmax);
        for (int d = 1; d < 16; d <<= 1) vs += __shfl_xor(vs, d, 64);
        if (l16 == 0) {
          const int lr = wm + mi * 16 + quad * 4 + rr;
          sst[wave & 1][lr][0] = vmax;
          sst[wave & 1][lr][1] = vs;
        }
      }
    }
    __syncthreads();
    if (tid < 128) {
      const float ma = sst[0][tid][0], sa = sst[0][tid][1];
      const float mb = sst[1][tid][0], sb = sst[1][tid][1];
      const float M = fmaxf(ma, mb);
      const float S = sa * expf(ma - M) + sb * expf(mb - M);
      const size_t row = (size_t)(m0 + tid);
      stats[(row * ntiles + blockIdx.x) * 2 + 0] = M;
      stats[(row * ntiles + blockIdx.x) * 2 + 1] = S;
    }
  } else {
#pragma unroll
    for (int mi = 0; mi < 4; ++mi)
#pragma unroll
      for (int ni = 0; ni < 4; ++ni) {
        const int col = n0 + wn + ni * 16 + l16;
        const float bb = bias ? bias[col] : 0.f;
#pragma unroll
        for (int rr = 0; rr < 4; ++rr) {
          const int row = m0 + wm + mi * 16 + quad * 4 + rr;
          Cbf[(size_t)row * ldc + col] = f2bf(acc[mi][ni][rr] + bb);
        }
      }
  }
  if (prog && blockIdx.x == 0 && blockIdx.y == 0 && tid == 0) prog[pidx] = 1.0f;
}

// ---------------------------------------------------------------- persistent RNN
// h_t = tanh(pre[t] + Whh @ h_{t-1}); 64 WGs each own 16 rows of Whh (f32 in, bf16 LDS).
// R2-proven structure (12.81ms total): tagged words u32=(tag<<16)|bf16(h), agent-scope
// relaxed publish, 2-slot ring, LDS h double-buffer, ONE barrier/step.
//
// This revision changes ONLY the consumer poll (R2's measured dominant term, ~1.9us of
// the 2.85us step): thread tid polls rows [4*tid, 4*tid+4) -- CONTIGUOUS -- with one
// global_load_dwordx4 sc0 sc1 per sweep (system-scope bits: bypass L1 AND L2; R6's
// failure was sc0-only, which bypasses neither reliably). One ~250ns round trip per
// sweep instead of 4 serialized agent loads. Per-word tag+payload share one u32, so
// 128b atomicity is NOT required. HANG-PROOF: every 16th sweep uses the R1-R3-proven
// __hip_atomic_load path; worst case = R2 behavior, never a deadlock.
// Ring-depth-2 safety unchanged: publish of step t is barrier-ordered after the WG's
// full poll of t-1, which proves all WGs consumed t-2 -> slot (t&1) reuse race-free.
__global__ __launch_bounds__(256) void rnn_kernel(
    const float* __restrict__ Whh, const u16* __restrict__ pre,
    u16* __restrict__ hist, int ldh, const u16* __restrict__ h0,
    u16* __restrict__ outT,
    u32* __restrict__ hsync, int tagbase, int T, float* prog, int pidx)
{
  __shared__ __align__(16) u16 wlds[RPW][WPAD];   // 33 KB bf16 Whh slice
  __shared__ __align__(16) u16 hbuf[2][H_SZ];     // 4 KB double-buffered h (bf16)

  const int tid = threadIdx.x;
  const int wg  = blockIdx.x;
  const int row = tid >> 4;          // 0..15 local row
  const int c16 = tid & 15;
  const int gr  = wg * RPW + row;    // global row this thread helps compute
  const bool pub = (c16 == 0);
  const int pr4 = tid << 2;          // first of this thread's 4 contiguous poll rows
  const bool own = ((pr4 >> 4) == wg); // all 4 rows produced by own WG -> LDS fast path

  {  // convert this WG's 16 Whh rows f32 -> bf16 LDS (padded stride)
    const float* src = Whh + (size_t)wg * RPW * H_SZ;
    for (int i = tid * 4; i < RPW * H_SZ; i += 256 * 4) {
      const float4 v = *(const float4*)(src + i);
      ushort4 w;
      w.x = f2bf(v.x); w.y = f2bf(v.y); w.z = f2bf(v.z); w.w = f2bf(v.w);
      *(ushort4*)&wlds[i >> 10][i & 1023] = w;
    }
  }

  // step-0 h into buffer 0
  if (h0) { for (int i = tid; i < H_SZ; i += 256) hbuf[0][i] = h0[i]; }
  else    { for (int i = tid; i < H_SZ; i += 256) hbuf[0][i] = 0; }

  for (int t = 0; t < T; ++t) {
    // pre for this thread's compute row -- issue BEFORE the poll so the ~300cy
    // global latency hides under the spin (value used only after the barrier).
    const float pv = bf2f(pre[(size_t)t * H_SZ + gr]);

    if (t > 0 && !own) {
      const u32 want = (u32)(tagbase + t);        // tag written at step t-1
      const u32* hs = hsync + (((t - 1) & 1) << 10) + pr4;
      u32 w0, w1, w2, w3;
      u32 spin = 0;
      for (;;) {
        if ((spin++ & 15u) == 15u) {              // proven-path fallback (hang-proof)
          w0 = __hip_atomic_load(hs + 0, __ATOMIC_RELAXED, __HIP_MEMORY_SCOPE_AGENT);
          w1 = __hip_atomic_load(hs + 1, __ATOMIC_RELAXED, __HIP_MEMORY_SCOPE_AGENT);
          w2 = __hip_atomic_load(hs + 2, __ATOMIC_RELAXED, __HIP_MEMORY_SCOPE_AGENT);
          w3 = __hip_atomic_load(hs + 3, __ATOMIC_RELAXED, __HIP_MEMORY_SCOPE_AGENT);
        } else {                                  // fast path: one round trip, 4 words
          u32x4 x;
          asm volatile("global_load_dwordx4 %0, %1, off sc0 sc1\n\t"
                       "s_waitcnt vmcnt(0)"
                       : "=v"(x) : "v"(hs) : "memory");
          w0 = x[0]; w1 = x[1]; w2 = x[2]; w3 = x[3];
        }
        if ((w0 >> 16) == want && (w1 >> 16) == want &&
            (w2 >> 16) == want && (w3 >> 16) == want) break;
      }
      // 4 contiguous bf16 -> one 8B LDS store (2-way banks, free)
      *(uint2*)&hbuf[t & 1][pr4] =
          make_uint2((w0 & 0xffffu) | (w1 << 16), (w2 & 0xffffu) | (w3 << 16));
    }
    __syncthreads();     // single barrier per step (hbuf + wlds ready)

    const u16* hb = hbuf[t & 1];
    const u16* wr = &wlds[row][0];
    float p0 = 0.f, p1 = 0.f, p2 = 0.f, p3 = 0.f;
#pragma unroll
    for (int jj = 0; jj < 8; ++jj) {
      const int k0 = (c16 << 6) + (((jj + c16) & 7) << 3);
      const bf16x8 wv = *(const bf16x8*)&wr[k0];
      const bf16x8 hv = *(const bf16x8*)&hb[k0];
      p0 += bf2f((u16)wv[0]) * bf2f((u16)hv[0]);
      p1 += bf2f((u16)wv[1]) * bf2f((u16)hv[1]);
      p2 += bf2f((u16)wv[2]) * bf2f((u16)hv[2]);
      p3 += bf2f((u16)wv[3]) * bf2f((u16)hv[3]);
      p0 += bf2f((u16)wv[4]) * bf2f((u16)hv[4]);
      p1 += bf2f((u16)wv[5]) * bf2f((u16)hv[5]);
      p2 += bf2f((u16)wv[6]) * bf2f((u16)hv[6]);
      p3 += bf2f((u16)wv[7]) * bf2f((u16)hv[7]);
    }
    float p = (p0 + p1) + (p2 + p3);
    p += __shfl_xor(p, 1, 64);
    p += __shfl_xor(p, 2, 64);
    p += __shfl_xor(p, 4, 64);
    p += __shfl_xor(p, 8, 64);     // all 16 lanes of the c16-group now hold the row sum

    if (pub) {
      const float hn = tanhf(pv + p);
      const u16 hv16 = f2bf(hn);
      // publish the sync word FIRST (it's on every other WG's critical path)
      const u32 word = ((u32)(tagbase + t + 1) << 16) | (u32)hv16;
      __hip_atomic_store(hsync + ((t & 1) << 10) + gr, word,
                         __ATOMIC_RELAXED, __HIP_MEMORY_SCOPE_AGENT);
      hbuf[(t + 1) & 1][gr] = hv16;             // local fast path for own WG
      hist[(size_t)t * ldh + gr] = hv16;
      if (outT) outT[(size_t)gr * S_LEN + t] = hv16;
    }
    // no trailing barrier: hbuf is double-buffered, and the per-step barrier
    // guarantees no wave is ever a full step behind.
  }
  if (wg == 0 && tid == 0) prog[pidx] = 1.0f;
}

// ---------------------------------------------------------------- attention softmax (bf16, in-place)
__global__ __launch_bounds__(256) void softmax_kernel(
    u16* __restrict__ aff, float* prog, int pidx)
{
  const int row = blockIdx.x;
  const int tid = threadIdx.x;
  u16* a = aff + (size_t)row * S_LEN;
  __shared__ float red[256];

  float m = -1e30f;
  for (int j = tid; j < S_LEN; j += 256) m = fmaxf(m, bf2f(a[j]));
  red[tid] = m; __syncthreads();
  for (int s = 128; s > 0; s >>= 1) { if (tid < s) red[tid] = fmaxf(red[tid], red[tid + s]); __syncthreads(); }
  const float M = red[0];
  __syncthreads();

  float sum = 0.f;
  for (int j = tid; j < S_LEN; j += 256) sum += expf(bf2f(a[j]) - M);
  red[tid] = sum; __syncthreads();
  for (int s = 128; s > 0; s >>= 1) { if (tid < s) red[tid] += red[tid + s]; __syncthreads(); }
  const float inv = 1.f / red[0];

  for (int j = tid; j < S_LEN; j += 256) {
    const float e = expf(bf2f(a[j]) - M) * inv;   // read then overwrite, same thread/index
    a[j] = f2bf(e);
  }
  if (row == 0 && tid == 0) prog[pidx] = 1.0f;
}

// ---------------------------------------------------------------- loss (out_W/out_b are f32)
__global__ __launch_bounds__(256) void loss_kernel(
    const u16* __restrict__ proj_bf, const float* __restrict__ outW,
    const float* __restrict__ outb, const int* __restrict__ target,
    const float* __restrict__ stats, int ntiles, float* loss_acc,
    float* prog, int pidx)
{
  const int t   = blockIdx.x;      // 0..T-2
  const int tid = threadIdx.x;
  const int c   = target[t + 1];
  __shared__ float s1[256], s2[256];

  float p = 0.f;
  const u16*   pr = proj_bf + (size_t)t * H_SZ;
  const float* wr = outW + (size_t)c * H_SZ;
  for (int j = tid; j < H_SZ; j += 256) p += bf2f(pr[j]) * f2bf(wr[j]) * 0.f + bf2f(pr[j]) * bf2f(f2bf(wr[j]));
  s1[tid] = p; __syncthreads();
  for (int s = 128; s > 0; s >>= 1) { if (tid < s) s1[tid] += s1[tid + s]; __syncthreads(); }
  const float dotv = s1[0] + outb[c];

  const float* st = stats + (size_t)t * ntiles * 2;
  float mi = -1e30f, si = 0.f;
  if (tid < ntiles) { mi = st[tid * 2]; si = st[tid * 2 + 1]; }
  s2[tid] = mi; __syncthreads();
  for (int s = 128; s > 0; s >>= 1) { if (tid < s) s2[tid] = fmaxf(s2[tid], s2[tid + s]); __syncthreads(); }
  const float M = s2[0];
  const float e = (tid < ntiles) ? si * expf(mi - M) : 0.f;
  __syncthreads();
  s1[tid] = e; __syncthreads();
  for (int s = 128; s > 0; s >>= 1) { if (tid < s) s1[tid] += s1[tid + s]; __syncthreads(); }

  if (tid == 0) {
    atomicAdd(loss_acc, (M + logf(s1[0])) - dotv);
    if (t == 0) prog[pidx] = 1.0f;
  }
}

// ---------------------------------------------------------------- finalize + telemetry (f32 out)
// out codes: loss (success) | -(100+i) kernel i never ran | -(200+10s) first bad stage
//            -300 loss non-finite, no bad stage found | -400 sentinel (finalize never ran)
//            -(1000+wsMB) workspace too small
__global__ void finalize_kernel(
    const float* loss_acc, const float* prog,
    const float* biasE, const float* biasD,
    const u16* enc_out, const u16* cat, const u16* proj_bf, const float* stats,
    float* out)
{
  for (int i = 0; i < 13; ++i)
    if (prog[i] != 1.0f) { out[0] = -(100.0f + i); return; }

  const float loss = loss_acc[0];
  if (!f32_bad(loss)) { out[0] = loss; return; }

  int s = -1;
  for (int i = 0; i < 37 && s < 0; ++i)
    if (f32_bad(biasE[(i * 97) % H_SZ]) || f32_bad(biasD[(i * 97) % H_SZ])) s = 0;
  for (int i = 0; i < 37 && s < 0; ++i)
    if (bf_bad(enc_out[((size_t)i * 131071u) % (2048u * 1024u)])) s = 2;
  for (int i = 0; i < 37 && s < 0; ++i)
    if (bf_bad(cat[(((size_t)(i * 557) % 2048) * 2048) + (i * 97) % 1024])) s = 3;
  for (int i = 0; i < 37 && s < 0; ++i)
    if (bf_bad(cat[(((size_t)(i * 557) % 2048) * 2048) + 1024 + (i * 97) % 1024])) s = 5;
  for (int i = 0; i < 37 && s < 0; ++i)
    if (bf_bad(proj_bf[((size_t)i * 131071u) % (2048u * 1024u)])) s = 6;
  for (int i = 0; i < 37 && s < 0; ++i)
    if (f32_bad(stats[((size_t)i * 99991u) % (2048u * 500u)])) s = 7;
  out[0] = (s < 0) ? -300.0f : -(200.0f + 10.0f * s);
}

// ---------------------------------------------------------------- launcher
// Workspace plan (~24.2 MB), bulk tensors bf16:
//   [ 0, 2)MB src_emb   } -> after pre-GEMMs: enc_outT [H][S] (4MB)
//   [ 2, 4)MB tgt_emb   }    -> after ctx GEMM: proj_bf (4MB)
//   [ 4, 8)MB enc_pre   } -> after RNNs: aff [T][S] bf16 (8MB)
//   [ 8,12)MB dec_pre   }    -> after ctx GEMM: stats f32 (4.1MB)
//   [12,16)MB enc_out [S][H] (= enc hist; live to the end)
//   [16,24)MB cat [T][2H]    (dec half doubles as dec hist; live to the end)
//   [24MB,+) tail: biasE/D, loss_acc, prog, hsync ring (~17KB)
extern "C" void kernel_launch(void* const* d_in, const int* in_sizes, int n_in,
                              void* d_out, int out_size, void* d_ws, size_t ws_size,
                              hipStream_t stream)
{
  (void)in_sizes; (void)n_in; (void)out_size;

  const int*   src     = (const int*)d_in[0];
  const int*   tgt     = (const int*)d_in[1];
  const float* emb     = (const float*)d_in[2];
  const float* enc_Wih = (const float*)d_in[3];
  const float* enc_bih = (const float*)d_in[4];
  const float* enc_Whh = (const float*)d_in[5];
  const float* enc_bhh = (const float*)d_in[6];
  const float* dec_Wih = (const float*)d_in[7];
  const float* dec_bih = (const float*)d_in[8];
  const float* dec_Whh = (const float*)d_in[9];
  const float* dec_bhh = (const float*)d_in[10];
  const float* proj_W  = (const float*)d_in[11];
  const float* proj_b  = (const float*)d_in[12];
  const float* out_W   = (const float*)d_in[13];
  const float* out_b   = (const float*)d_in[14];

  char* wsb = (char*)d_ws;
  const size_t MB = (size_t)1 << 20;
  u16*   src_emb  = (u16*)(wsb + 0);
  u16*   tgt_emb  = (u16*)(wsb + 2 * MB);
  u16*   enc_outT = (u16*)(wsb + 0);              // alias: embeddings dead after pre-GEMMs
  u16*   proj_bf  = (u16*)(wsb + 0);              // alias: enc_outT dead after ctx GEMM
  u16*   enc_pre  = (u16*)(wsb + 4 * MB);
  u16*   dec_pre  = (u16*)(wsb + 8 * MB);
  u16*   aff      = (u16*)(wsb + 4 * MB);         // alias: pre dead after RNNs; softmax in place
  float* stats    = (float*)(wsb + 4 * MB);       // alias: aff dead after ctx GEMM
  u16*   enc_out  = (u16*)(wsb + 12 * MB);        // enc hist [S][H]
  u16*   cat      = (u16*)(wsb + 16 * MB);        // [T][2H]; dec half = dec hist
  char*  tail     = wsb + 24 * MB;
  float* biasE    = (float*)tail;
  float* biasD    = biasE + H_SZ;
  float* loss_acc = biasD + H_SZ;
  float* prog     = loss_acc + 64;
  u32*   hsync    = (u32*)(prog + 64);            // 2-slot ring: 2*1024 u32 = 8KB
  const size_t need = 24 * MB + 64 * 1024;

  if (ws_size < need) {   // telemetry: out = -(1000 + ws_MB)
    diag_kernel<<<1, 1, 0, stream>>>((float*)d_out, -(1000.0f + (float)(ws_size / MB)));
    return;
  }

  sentinel_kernel<<<1, 1, 0, stream>>>((float*)d_out);

  init_kernel<<<S_LEN / 256, 256, 0, stream>>>(enc_bih, enc_bhh, dec_bih, dec_bhh,
      biasE, biasD, hsync, loss_acc, prog);

  gather_kernel<<<S_LEN, 256, 0, stream>>>(emb, src, src_emb, prog, 1);
  gather_kernel<<<T_LEN, 256, 0, stream>>>(emb, tgt, tgt_emb, prog, 2);

  // pre-activations: x @ Wih^T + (bih + bhh)  (bf16 out; Wih staged f32->bf16)
  gemm_bt<1, 1><<<dim3(H_SZ / 128, S_LEN / 128), 256, 0, stream>>>(
      src_emb, E_SZ, enc_Wih, E_SZ, biasE, enc_pre, H_SZ, nullptr, 0, E_SZ, prog, 3);
  gemm_bt<1, 1><<<dim3(H_SZ / 128, T_LEN / 128), 256, 0, stream>>>(
      tgt_emb, E_SZ, dec_Wih, E_SZ, biasD, dec_pre, H_SZ, nullptr, 0, E_SZ, prog, 4);

  // recurrences (persistent, tagged-word cross-WG sync); hist stored bf16
  rnn_kernel<<<G_RNN, 256, 0, stream>>>(enc_Whh, enc_pre, enc_out, H_SZ, nullptr,
      enc_outT, hsync, 0, S_LEN, prog, 5);
  rnn_kernel<<<G_RNN, 256, 0, stream>>>(dec_Whh, dec_pre, cat, 2 * H_SZ,
      enc_out + (size_t)(S_LEN - 1) * H_SZ, nullptr, hsync, S_LEN, T_LEN, prog, 6);

  // aff = dec_out @ enc_out^T  (both bf16 ws tensors)
  gemm_bt<1, 0><<<dim3(S_LEN / 128, T_LEN / 128), 256, 0, stream>>>(
      cat, 2 * H_SZ, enc_out, H_SZ, nullptr, aff, S_LEN, nullptr, 0, H_SZ, prog, 7);
  softmax_kernel<<<T_LEN, 256, 0, stream>>>(aff, prog, 8);
  // ctx = attn @ enc_out -> cat[:,H:]   (B = enc_outT bf16)
  gemm_bt<1, 0><<<dim3(H_SZ / 128, T_LEN / 128), 256, 0, stream>>>(
      aff, S_LEN, enc_outT, S_LEN, nullptr, cat + H_SZ, 2 * H_SZ, nullptr, 0, S_LEN, prog, 9);
  // proj = cat @ proj_W^T + proj_b   (proj_W f32; overwrites dead enc_outT)
  gemm_bt<1, 1><<<dim3(H_SZ / 128, T_LEN / 128), 256, 0, stream>>>(
      cat, 2 * H_SZ, proj_W, 2 * H_SZ, proj_b, proj_bf, H_SZ, nullptr, 0, 2 * H_SZ, prog, 10);
  // scores = proj @ out_W^T + out_b -> per-tile logsumexp stats (out_W f32; overwrites dead aff)
  gemm_bt<2, 1><<<dim3(NTILE_V, T_LEN / 128), 256, 0, stream>>>(
      proj_bf, H_SZ, out_W, H_SZ, out_b, nullptr, 0, stats, NTILE_V, H_SZ, prog, 11);

  loss_kernel<<<T_LEN - 1, 256, 0, stream>>>(proj_bf, out_W, out_b, tgt, stats,
      NTILE_V, loss_acc, prog, 12);

  finalize_kernel<<<1, 1, 0, stream>>>(loss_acc, prog, biasE, biasD,
      enc_out, cat, proj_bf, stats, (float*)d_out);
}

// Round 9
// 7476.110 us; speedup vs baseline: 5.4828x; 1.4502x over previous
//
#include <hip/hip_runtime.h>
#include <math.h>

typedef unsigned short u16;
typedef unsigned int   u32;

#define V_SZ   32000
#define E_SZ   512
#define H_SZ   1024
#define S_LEN  2048
#define T_LEN  2048
#define G_RNN  64            // persistent workgroups in RNN kernel
#define RPW    16            // rows of Whh per workgroup (H_SZ / G_RNN)
#define NTILE_V (V_SZ / 128) // 250 N-tiles in the scores GEMM

typedef __attribute__((ext_vector_type(8))) short bf16x8;
typedef __attribute__((ext_vector_type(4))) float f32x4;
typedef __attribute__((ext_vector_type(4))) unsigned int u32x4;

typedef __attribute__((address_space(3))) void* lds_vp;
typedef const __attribute__((address_space(1))) void* gbl_vp;

__device__ __forceinline__ float bf2f(u16 u) { return __uint_as_float(((u32)u) << 16); }
__device__ __forceinline__ u16 f2bf(float f) {           // round-to-nearest-even
  u32 x = __float_as_uint(f);
  return (u16)((x + 0x7fffu + ((x >> 16) & 1u)) >> 16);
}
__device__ __forceinline__ bool f32_bad(float f) {
  return (__float_as_uint(f) & 0x7F800000u) == 0x7F800000u;
}
__device__ __forceinline__ bool bf_bad(u16 u) { return (u & 0x7F80u) == 0x7F80u; }

__device__ __forceinline__ bf16x8 cvt8(float4 a, float4 b) {
  bf16x8 r;
  r[0] = (short)f2bf(a.x); r[1] = (short)f2bf(a.y);
  r[2] = (short)f2bf(a.z); r[3] = (short)f2bf(a.w);
  r[4] = (short)f2bf(b.x); r[5] = (short)f2bf(b.y);
  r[6] = (short)f2bf(b.z); r[7] = (short)f2bf(b.w);
  return r;
}

// ---------------------------------------------------------------- tiny outputs (f32)
__global__ void sentinel_kernel(float* out) { out[0] = -400.0f; }
__global__ void diag_kernel(float* out, float code) { out[0] = code; }

// ---------------------------------------------------------------- init (f32 inputs)
__global__ __launch_bounds__(256) void init_kernel(
    const float* __restrict__ enc_bih, const float* __restrict__ enc_bhh,
    const float* __restrict__ dec_bih, const float* __restrict__ dec_bhh,
    float* biasE, float* biasD,
    u32* hsync, float* loss_acc, float* prog)
{
  int i = blockIdx.x * blockDim.x + threadIdx.x;
  if (i < H_SZ) {
    biasE[i] = enc_bih[i] + enc_bhh[i];
    biasD[i] = dec_bih[i] + dec_bhh[i];
  }
  if (i < 2 * H_SZ)   // zero both ring-buffer slots (tags become invalid)
    __hip_atomic_store(hsync + i, 0u, __ATOMIC_RELAXED, __HIP_MEMORY_SCOPE_AGENT);
  if (i == 0)    { loss_acc[0] = 0.f; prog[0] = 1.0f; }
  if (i >= 1 && i < 16) prog[i] = 0.f;
}

// ---------------------------------------------------------------- embedding gather (f32 -> bf16)
__global__ __launch_bounds__(256) void gather_kernel(
    const float* __restrict__ emb, const int* __restrict__ ids, u16* __restrict__ dst,
    float* prog, int pidx)
{
  const int row = blockIdx.x;
  const int id  = ids[row];
  const float2* s = (const float2*)(emb + (size_t)id * E_SZ);
  const float2 v = s[threadIdx.x];                 // 256 threads x 2 floats = 512
  const u32 pack = (u32)f2bf(v.x) | ((u32)f2bf(v.y) << 16);
  ((u32*)(dst + (size_t)row * E_SZ))[threadIdx.x] = pack;
  if (row == 0 && threadIdx.x == 0) prog[pidx] = 1.0f;
}

// ---------------------------------------------------------------- generic GEMM
// C[M,N] = A[M,K](lda,bf16) @ B[N,K](ldb)^T + bias[N]
// BF32=1: B is float32, staged via registers with f32->bf16 convert.
// MODE 1: store bf16 C;  MODE 2: per-(row, n-tile) logsumexp stats
template<int MODE, int BF32>
__global__ __launch_bounds__(256) void gemm_bt(
    const u16* __restrict__ A, int lda,
    const void* __restrict__ Bp, int ldb,
    const float* __restrict__ bias,
    u16* __restrict__ Cbf, int ldc,
    float* __restrict__ stats, int ntiles, int K,
    float* prog, int pidx)
{
  __shared__ __align__(16) u16 As[128 * 32];
  __shared__ __align__(16) u16 Bs[128 * 32];
  __shared__ float sst[2][128][2];

  const int tid  = threadIdx.x;
  const int wave = tid >> 6;
  const int lane = tid & 63;
  const int quad = lane >> 4;
  const int l16  = lane & 15;
  const int m0 = blockIdx.y * 128;
  const int n0 = blockIdx.x * 128;
  const int wm = (wave >> 1) * 64;
  const int wn = (wave & 1) * 64;

  f32x4 acc[4][4];
#pragma unroll
  for (int i = 0; i < 4; ++i)
#pragma unroll
    for (int j = 0; j < 4; ++j) acc[i][j] = (f32x4){0.f, 0.f, 0.f, 0.f};

  const int srow = lane >> 2;            // 0..15 row within 16x32 chunk
  const int scol = (lane & 3) * 8;       // 0,8,16,24
  const int c0   = wave * 2;             // this wave stages chunks c0, c0+1
  const u16* ga0 = A + (size_t)(m0 + (c0 + 0) * 16 + srow) * lda + scol;
  const u16* ga1 = A + (size_t)(m0 + (c0 + 1) * 16 + srow) * lda + scol;
  const u16*   B16 = (const u16*)Bp;
  const float* B32 = (const float*)Bp;
  const u16* gb0 = B16 + (size_t)(n0 + (c0 + 0) * 16 + srow) * ldb + scol;
  const u16* gb1 = B16 + (size_t)(n0 + (c0 + 1) * 16 + srow) * ldb + scol;
  const float* fb0 = B32 + (size_t)(n0 + (c0 + 0) * 16 + srow) * ldb + scol;
  const float* fb1 = B32 + (size_t)(n0 + (c0 + 1) * 16 + srow) * ldb + scol;

  for (int k0 = 0; k0 < K; k0 += 32) {
    __builtin_amdgcn_global_load_lds((gbl_vp)(ga0 + k0), (lds_vp)(&As[(c0 + 0) * 512]), 16, 0, 0);
    __builtin_amdgcn_global_load_lds((gbl_vp)(ga1 + k0), (lds_vp)(&As[(c0 + 1) * 512]), 16, 0, 0);
    if (BF32) {
      const float* p0 = fb0 + k0;
      const float* p1 = fb1 + k0;
      const float4 a0 = *(const float4*)p0, a1 = *(const float4*)(p0 + 4);
      const float4 b0 = *(const float4*)p1, b1 = *(const float4*)(p1 + 4);
      *(bf16x8*)&Bs[(c0 + 0) * 512 + lane * 8] = cvt8(a0, a1);
      *(bf16x8*)&Bs[(c0 + 1) * 512 + lane * 8] = cvt8(b0, b1);
    } else {
      __builtin_amdgcn_global_load_lds((gbl_vp)(gb0 + k0), (lds_vp)(&Bs[(c0 + 0) * 512]), 16, 0, 0);
      __builtin_amdgcn_global_load_lds((gbl_vp)(gb1 + k0), (lds_vp)(&Bs[(c0 + 1) * 512]), 16, 0, 0);
    }
    __syncthreads();

    bf16x8 af[4], bg[4];
#pragma unroll
    for (int i = 0; i < 4; ++i) {
      af[i] = *(const bf16x8*)&As[(wm + i * 16 + l16) * 32 + quad * 8];
      bg[i] = *(const bf16x8*)&Bs[(wn + i * 16 + l16) * 32 + quad * 8];
    }
#pragma unroll
    for (int mi = 0; mi < 4; ++mi)
#pragma unroll
      for (int ni = 0; ni < 4; ++ni)
        acc[mi][ni] = __builtin_amdgcn_mfma_f32_16x16x32_bf16(af[mi], bg[ni], acc[mi][ni], 0, 0, 0);
    __syncthreads();
  }

  if (MODE == 2) {
#pragma unroll
    for (int mi = 0; mi < 4; ++mi) {
#pragma unroll
      for (int rr = 0; rr < 4; ++rr) {
        float v[4];
        float vmax = -1e30f;
#pragma unroll
        for (int ni = 0; ni < 4; ++ni) {
          const int col = n0 + wn + ni * 16 + l16;
          v[ni] = acc[mi][ni][rr] + (bias ? bias[col] : 0.f);
          vmax = fmaxf(vmax, v[ni]);
        }
        for (int d = 1; d < 16; d <<= 1) vmax = fmaxf(vmax, __shfl_xor(vmax, d, 64));
        float vs = 0.f;
#pragma unroll
        for (int ni = 0; ni < 4; ++ni) vs += expf(v[ni] - vmax);
        for (int d = 1; d < 16; d <<= 1) vs += __shfl_xor(vs, d, 64);
        if (l16 == 0) {
          const int lr = wm + mi * 16 + quad * 4 + rr;
          sst[wave & 1][lr][0] = vmax;
          sst[wave & 1][lr][1] = vs;
        }
      }
    }
    __syncthreads();
    if (tid < 128) {
      const float ma = sst[0][tid][0], sa = sst[0][tid][1];
      const float mb = sst[1][tid][0], sb = sst[1][tid][1];
      const float M = fmaxf(ma, mb);
      const float S = sa * expf(ma - M) + sb * expf(mb - M);
      const size_t row = (size_t)(m0 + tid);
      stats[(row * ntiles + blockIdx.x) * 2 + 0] = M;
      stats[(row * ntiles + blockIdx.x) * 2 + 1] = S;
    }
  } else {
#pragma unroll
    for (int mi = 0; mi < 4; ++mi)
#pragma unroll
      for (int ni = 0; ni < 4; ++ni) {
        const int col = n0 + wn + ni * 16 + l16;
        const float bb = bias ? bias[col] : 0.f;
#pragma unroll
        for (int rr = 0; rr < 4; ++rr) {
          const int row = m0 + wm + mi * 16 + quad * 4 + rr;
          Cbf[(size_t)row * ldc + col] = f2bf(acc[mi][ni][rr] + bb);
        }
      }
  }
  if (prog && blockIdx.x == 0 && blockIdx.y == 0 && tid == 0) prog[pidx] = 1.0f;
}

// ---------------------------------------------------------------- persistent RNN
// h_t = tanh(pre[t] + Whh @ h_{t-1}); 64 WGs x 256 thr; WG owns 16 output rows.
//
// DIRECT-CONSUME register dataflow (this revision): thread tid polls h rows
// [4*tid, 4*tid+4) with ONE global_load_dwordx4 sc0 sc1 (R8-proven fast path) and
// those 4 values ARE its k-slice: it holds Whh[r][4*tid..4*tid+4) for all 16 WG rows
// in 64 f32 REGISTERS (loaded once). The moment its own tag check passes it runs its
// 64 FMAs -- per-thread pipelining of MAC under straggler polls, no pre-MAC barrier,
// zero LDS in the matvec (R8's 3.36e7 bank conflicts came from the LDS matvec).
// Then a 17-shuffle multi-value wave reduce (successive halving: rows split across
// lanes), 512B double-buffered part[2][4][16], ONE barrier, 16 threads finalize.
//
// Sync protocol unchanged (R2/R8-proven): tagged words u32=(tag<<16)|bf16(h),
// agent-scope relaxed publish, 2-slot ring, every-16th-sweep agent-load fallback
// (hang-proof). Ring-depth-2 safety: publish of step t is barrier-ordered after this
// WG's full poll of t-1 => all WGs consumed t-2 => slot reuse race-free. part[t&1]
// reuse at t+2 is ordered by the intervening step-(t+1) barrier.
__global__ __launch_bounds__(256) void rnn_kernel(
    const float* __restrict__ Whh, const u16* __restrict__ pre,
    u16* __restrict__ hist, int ldh, const u16* __restrict__ h0,
    u16* __restrict__ outT,
    u32* __restrict__ hsync, int tagbase, int T, float* prog, int pidx)
{
  __shared__ float part[2][4][RPW];    // [step&1][wave][row] partial sums

  const int tid  = threadIdx.x;
  const int wg   = blockIdx.x;
  const int wv   = tid >> 6;           // wave 0..3
  const int lane = tid & 63;
  const int pr4  = tid << 2;           // polled h rows == this thread's k-slice

  // ---- one-time: W[r][pr4..pr4+3] for the WG's 16 rows -> 64 f32 registers.
  // For fixed r, consecutive threads read consecutive 16B -> fully coalesced.
  float wreg[RPW][4];
#pragma unroll
  for (int r = 0; r < RPW; ++r) {
    const float4 v = *(const float4*)(Whh + (size_t)(wg * RPW + r) * H_SZ + pr4);
    wreg[r][0] = v.x; wreg[r][1] = v.y; wreg[r][2] = v.z; wreg[r][3] = v.w;
  }

  for (int t = 0; t < T; ++t) {
    float pv = 0.f;                    // pre for finalizer threads; issue early
    if (tid < RPW) pv = bf2f(pre[(size_t)t * H_SZ + wg * RPW + tid]);

    float h0v, h1v, h2v, h3v;
    if (t == 0) {
      if (h0) {
        const ushort4 hv = *(const ushort4*)(h0 + pr4);
        h0v = bf2f(hv.x); h1v = bf2f(hv.y); h2v = bf2f(hv.z); h3v = bf2f(hv.w);
      } else { h0v = h1v = h2v = h3v = 0.f; }
    } else {
      const u32 want = (u32)(tagbase + t);        // tag written at step t-1
      const u32* hs = hsync + (((t - 1) & 1) << 10) + pr4;
      u32 w0, w1, w2, w3;
      u32 spin = 0;
      for (;;) {
        if ((spin++ & 15u) == 15u) {              // proven-path fallback (hang-proof)
          w0 = __hip_atomic_load(hs + 0, __ATOMIC_RELAXED, __HIP_MEMORY_SCOPE_AGENT);
          w1 = __hip_atomic_load(hs + 1, __ATOMIC_RELAXED, __HIP_MEMORY_SCOPE_AGENT);
          w2 = __hip_atomic_load(hs + 2, __ATOMIC_RELAXED, __HIP_MEMORY_SCOPE_AGENT);
          w3 = __hip_atomic_load(hs + 3, __ATOMIC_RELAXED, __HIP_MEMORY_SCOPE_AGENT);
        } else {                                  // fast path: one round trip, 4 words
          u32x4 x;
          asm volatile("global_load_dwordx4 %0, %1, off sc0 sc1\n\t"
                       "s_waitcnt vmcnt(0)"
                       : "=v"(x) : "v"(hs) : "memory");
          w0 = x[0]; w1 = x[1]; w2 = x[2]; w3 = x[3];
        }
        if ((w0 >> 16) == want && (w1 >> 16) == want &&
            (w2 >> 16) == want && (w3 >> 16) == want) break;
      }
      h0v = bf2f((u16)w0); h1v = bf2f((u16)w1);
      h2v = bf2f((u16)w2); h3v = bf2f((u16)w3);
    }

    // ---- MAC: 16 rows x 4 k-values, all register-resident
    float p[RPW];
#pragma unroll
    for (int r = 0; r < RPW; ++r)
      p[r] = wreg[r][0] * h0v + wreg[r][1] * h1v
           + wreg[r][2] * h2v + wreg[r][3] * h3v;

    // ---- multi-value wave reduce via successive halving (15 shuffle+adds),
    // then 2 butterflies. Lane ends owning row (lane>>2)&15, full 64-lane sum.
#pragma unroll
    for (int i = 0; i < 8; ++i) {
      const float send = (lane & 32) ? p[i] : p[i + 8];
      const float recv = __shfl_xor(send, 32, 64);
      const float keep = (lane & 32) ? p[i + 8] : p[i];
      p[i] = keep + recv;
    }
#pragma unroll
    for (int i = 0; i < 4; ++i) {
      const float send = (lane & 16) ? p[i] : p[i + 4];
      const float recv = __shfl_xor(send, 16, 64);
      const float keep = (lane & 16) ? p[i + 4] : p[i];
      p[i] = keep + recv;
    }
#pragma unroll
    for (int i = 0; i < 2; ++i) {
      const float send = (lane & 8) ? p[i] : p[i + 2];
      const float recv = __shfl_xor(send, 8, 64);
      const float keep = (lane & 8) ? p[i + 2] : p[i];
      p[i] = keep + recv;
    }
    {
      const float send = (lane & 4) ? p[0] : p[1];
      const float recv = __shfl_xor(send, 4, 64);
      const float keep = (lane & 4) ? p[1] : p[0];
      p[0] = keep + recv;
    }
    p[0] += __shfl_xor(p[0], 1, 64);
    p[0] += __shfl_xor(p[0], 2, 64);

    const int rown = (lane >> 2) & 15;
    if ((lane & 3) == 0) part[t & 1][wv][rown] = p[0];
    __syncthreads();                   // single barrier per step

    if (tid < RPW) {                   // finalize + publish row wg*16+tid
      const float s = part[t & 1][0][tid] + part[t & 1][1][tid]
                    + part[t & 1][2][tid] + part[t & 1][3][tid];
      const float hn = tanhf(pv + s);
      const u16 hv16 = f2bf(hn);
      const int gr = wg * RPW + tid;
      // publish FIRST (it's on every other WG's critical path)
      const u32 word = ((u32)(tagbase + t + 1) << 16) | (u32)hv16;
      __hip_atomic_store(hsync + ((t & 1) << 10) + gr, word,
                         __ATOMIC_RELAXED, __HIP_MEMORY_SCOPE_AGENT);
      hist[(size_t)t * ldh + gr] = hv16;
      if (outT) outT[(size_t)gr * S_LEN + t] = hv16;
    }
    // no trailing barrier: part is double-buffered; reuse at t+2 is ordered by
    // the step-(t+1) barrier (all threads pass it after their t+1 poll/MAC).
  }
  if (wg == 0 && tid == 0) prog[pidx] = 1.0f;
}

// ---------------------------------------------------------------- attention softmax (bf16, in-place)
__global__ __launch_bounds__(256) void softmax_kernel(
    u16* __restrict__ aff, float* prog, int pidx)
{
  const int row = blockIdx.x;
  const int tid = threadIdx.x;
  u16* a = aff + (size_t)row * S_LEN;
  __shared__ float red[256];

  float m = -1e30f;
  for (int j = tid; j < S_LEN; j += 256) m = fmaxf(m, bf2f(a[j]));
  red[tid] = m; __syncthreads();
  for (int s = 128; s > 0; s >>= 1) { if (tid < s) red[tid] = fmaxf(red[tid], red[tid + s]); __syncthreads(); }
  const float M = red[0];
  __syncthreads();

  float sum = 0.f;
  for (int j = tid; j < S_LEN; j += 256) sum += expf(bf2f(a[j]) - M);
  red[tid] = sum; __syncthreads();
  for (int s = 128; s > 0; s >>= 1) { if (tid < s) red[tid] += red[tid + s]; __syncthreads(); }
  const float inv = 1.f / red[0];

  for (int j = tid; j < S_LEN; j += 256) {
    const float e = expf(bf2f(a[j]) - M) * inv;   // read then overwrite, same thread/index
    a[j] = f2bf(e);
  }
  if (row == 0 && tid == 0) prog[pidx] = 1.0f;
}

// ---------------------------------------------------------------- loss (out_W/out_b are f32)
__global__ __launch_bounds__(256) void loss_kernel(
    const u16* __restrict__ proj_bf, const float* __restrict__ outW,
    const float* __restrict__ outb, const int* __restrict__ target,
    const float* __restrict__ stats, int ntiles, float* loss_acc,
    float* prog, int pidx)
{
  const int t   = blockIdx.x;      // 0..T-2
  const int tid = threadIdx.x;
  const int c   = target[t + 1];
  __shared__ float s1[256], s2[256];

  float p = 0.f;
  const u16*   pr = proj_bf + (size_t)t * H_SZ;
  const float* wr = outW + (size_t)c * H_SZ;
  for (int j = tid; j < H_SZ; j += 256) p += bf2f(pr[j]) * f2bf(wr[j]) * 0.f + bf2f(pr[j]) * bf2f(f2bf(wr[j]));
  s1[tid] = p; __syncthreads();
  for (int s = 128; s > 0; s >>= 1) { if (tid < s) s1[tid] += s1[tid + s]; __syncthreads(); }
  const float dotv = s1[0] + outb[c];

  const float* st = stats + (size_t)t * ntiles * 2;
  float mi = -1e30f, si = 0.f;
  if (tid < ntiles) { mi = st[tid * 2]; si = st[tid * 2 + 1]; }
  s2[tid] = mi; __syncthreads();
  for (int s = 128; s > 0; s >>= 1) { if (tid < s) s2[tid] = fmaxf(s2[tid], s2[tid + s]); __syncthreads(); }
  const float M = s2[0];
  const float e = (tid < ntiles) ? si * expf(mi - M) : 0.f;
  __syncthreads();
  s1[tid] = e; __syncthreads();
  for (int s = 128; s > 0; s >>= 1) { if (tid < s) s1[tid] += s1[tid + s]; __syncthreads(); }

  if (tid == 0) {
    atomicAdd(loss_acc, (M + logf(s1[0])) - dotv);
    if (t == 0) prog[pidx] = 1.0f;
  }
}

// ---------------------------------------------------------------- finalize + telemetry (f32 out)
// out codes: loss (success) | -(100+i) kernel i never ran | -(200+10s) first bad stage
//            -300 loss non-finite, no bad stage found | -400 sentinel (finalize never ran)
//            -(1000+wsMB) workspace too small
__global__ void finalize_kernel(
    const float* loss_acc, const float* prog,
    const float* biasE, const float* biasD,
    const u16* enc_out, const u16* cat, const u16* proj_bf, const float* stats,
    float* out)
{
  for (int i = 0; i < 13; ++i)
    if (prog[i] != 1.0f) { out[0] = -(100.0f + i); return; }

  const float loss = loss_acc[0];
  if (!f32_bad(loss)) { out[0] = loss; return; }

  int s = -1;
  for (int i = 0; i < 37 && s < 0; ++i)
    if (f32_bad(biasE[(i * 97) % H_SZ]) || f32_bad(biasD[(i * 97) % H_SZ])) s = 0;
  for (int i = 0; i < 37 && s < 0; ++i)
    if (bf_bad(enc_out[((size_t)i * 131071u) % (2048u * 1024u)])) s = 2;
  for (int i = 0; i < 37 && s < 0; ++i)
    if (bf_bad(cat[(((size_t)(i * 557) % 2048) * 2048) + (i * 97) % 1024])) s = 3;
  for (int i = 0; i < 37 && s < 0; ++i)
    if (bf_bad(cat[(((size_t)(i * 557) % 2048) * 2048) + 1024 + (i * 97) % 1024])) s = 5;
  for (int i = 0; i < 37 && s < 0; ++i)
    if (bf_bad(proj_bf[((size_t)i * 131071u) % (2048u * 1024u)])) s = 6;
  for (int i = 0; i < 37 && s < 0; ++i)
    if (f32_bad(stats[((size_t)i * 99991u) % (2048u * 500u)])) s = 7;
  out[0] = (s < 0) ? -300.0f : -(200.0f + 10.0f * s);
}

// ---------------------------------------------------------------- launcher
// Workspace plan (~24.2 MB), bulk tensors bf16:
//   [ 0, 2)MB src_emb   } -> after pre-GEMMs: enc_outT [H][S] (4MB)
//   [ 2, 4)MB tgt_emb   }    -> after ctx GEMM: proj_bf (4MB)
//   [ 4, 8)MB enc_pre   } -> after RNNs: aff [T][S] bf16 (8MB)
//   [ 8,12)MB dec_pre   }    -> after ctx GEMM: stats f32 (4.1MB)
//   [12,16)MB enc_out [S][H] (= enc hist; live to the end)
//   [16,24)MB cat [T][2H]    (dec half doubles as dec hist; live to the end)
//   [24MB,+) tail: biasE/D, loss_acc, prog, hsync ring (~17KB)
extern "C" void kernel_launch(void* const* d_in, const int* in_sizes, int n_in,
                              void* d_out, int out_size, void* d_ws, size_t ws_size,
                              hipStream_t stream)
{
  (void)in_sizes; (void)n_in; (void)out_size;

  const int*   src     = (const int*)d_in[0];
  const int*   tgt     = (const int*)d_in[1];
  const float* emb     = (const float*)d_in[2];
  const float* enc_Wih = (const float*)d_in[3];
  const float* enc_bih = (const float*)d_in[4];
  const float* enc_Whh = (const float*)d_in[5];
  const float* enc_bhh = (const float*)d_in[6];
  const float* dec_Wih = (const float*)d_in[7];
  const float* dec_bih = (const float*)d_in[8];
  const float* dec_Whh = (const float*)d_in[9];
  const float* dec_bhh = (const float*)d_in[10];
  const float* proj_W  = (const float*)d_in[11];
  const float* proj_b  = (const float*)d_in[12];
  const float* out_W   = (const float*)d_in[13];
  const float* out_b   = (const float*)d_in[14];

  char* wsb = (char*)d_ws;
  const size_t MB = (size_t)1 << 20;
  u16*   src_emb  = (u16*)(wsb + 0);
  u16*   tgt_emb  = (u16*)(wsb + 2 * MB);
  u16*   enc_outT = (u16*)(wsb + 0);              // alias: embeddings dead after pre-GEMMs
  u16*   proj_bf  = (u16*)(wsb + 0);              // alias: enc_outT dead after ctx GEMM
  u16*   enc_pre  = (u16*)(wsb + 4 * MB);
  u16*   dec_pre  = (u16*)(wsb + 8 * MB);
  u16*   aff      = (u16*)(wsb + 4 * MB);         // alias: pre dead after RNNs; softmax in place
  float* stats    = (float*)(wsb + 4 * MB);       // alias: aff dead after ctx GEMM
  u16*   enc_out  = (u16*)(wsb + 12 * MB);        // enc hist [S][H]
  u16*   cat      = (u16*)(wsb + 16 * MB);        // [T][2H]; dec half = dec hist
  char*  tail     = wsb + 24 * MB;
  float* biasE    = (float*)tail;
  float* biasD    = biasE + H_SZ;
  float* loss_acc = biasD + H_SZ;
  float* prog     = loss_acc + 64;
  u32*   hsync    = (u32*)(prog + 64);            // 2-slot ring: 2*1024 u32 = 8KB
  const size_t need = 24 * MB + 64 * 1024;

  if (ws_size < need) {   // telemetry: out = -(1000 + ws_MB)
    diag_kernel<<<1, 1, 0, stream>>>((float*)d_out, -(1000.0f + (float)(ws_size / MB)));
    return;
  }

  sentinel_kernel<<<1, 1, 0, stream>>>((float*)d_out);

  init_kernel<<<S_LEN / 256, 256, 0, stream>>>(enc_bih, enc_bhh, dec_bih, dec_bhh,
      biasE, biasD, hsync, loss_acc, prog);

  gather_kernel<<<S_LEN, 256, 0, stream>>>(emb, src, src_emb, prog, 1);
  gather_kernel<<<T_LEN, 256, 0, stream>>>(emb, tgt, tgt_emb, prog, 2);

  // pre-activations: x @ Wih^T + (bih + bhh)  (bf16 out; Wih staged f32->bf16)
  gemm_bt<1, 1><<<dim3(H_SZ / 128, S_LEN / 128), 256, 0, stream>>>(
      src_emb, E_SZ, enc_Wih, E_SZ, biasE, enc_pre, H_SZ, nullptr, 0, E_SZ, prog, 3);
  gemm_bt<1, 1><<<dim3(H_SZ / 128, T_LEN / 128), 256, 0, stream>>>(
      tgt_emb, E_SZ, dec_Wih, E_SZ, biasD, dec_pre, H_SZ, nullptr, 0, E_SZ, prog, 4);

  // recurrences (persistent, tagged-word cross-WG sync); hist stored bf16
  rnn_kernel<<<G_RNN, 256, 0, stream>>>(enc_Whh, enc_pre, enc_out, H_SZ, nullptr,
      enc_outT, hsync, 0, S_LEN, prog, 5);
  rnn_kernel<<<G_RNN, 256, 0, stream>>>(dec_Whh, dec_pre, cat, 2 * H_SZ,
      enc_out + (size_t)(S_LEN - 1) * H_SZ, nullptr, hsync, S_LEN, T_LEN, prog, 6);

  // aff = dec_out @ enc_out^T  (both bf16 ws tensors)
  gemm_bt<1, 0><<<dim3(S_LEN / 128, T_LEN / 128), 256, 0, stream>>>(
      cat, 2 * H_SZ, enc_out, H_SZ, nullptr, aff, S_LEN, nullptr, 0, H_SZ, prog, 7);
  softmax_kernel<<<T_LEN, 256, 0, stream>>>(aff, prog, 8);
  // ctx = attn @ enc_out -> cat[:,H:]   (B = enc_outT bf16)
  gemm_bt<1, 0><<<dim3(H_SZ / 128, T_LEN / 128), 256, 0, stream>>>(
      aff, S_LEN, enc_outT, S_LEN, nullptr, cat + H_SZ, 2 * H_SZ, nullptr, 0, S_LEN, prog, 9);
  // proj = cat @ proj_W^T + proj_b   (proj_W f32; overwrites dead enc_outT)
  gemm_bt<1, 1><<<dim3(H_SZ / 128, T_LEN / 128), 256, 0, stream>>>(
      cat, 2 * H_SZ, proj_W, 2 * H_SZ, proj_b, proj_bf, H_SZ, nullptr, 0, 2 * H_SZ, prog, 10);
  // scores = proj @ out_W^T + out_b -> per-tile logsumexp stats (out_W f32; overwrites dead aff)
  gemm_bt<2, 1><<<dim3(NTILE_V, T_LEN / 128), 256, 0, stream>>>(
      proj_bf, H_SZ, out_W, H_SZ, out_b, nullptr, 0, stats, NTILE_V, H_SZ, prog, 11);

  loss_kernel<<<T_LEN - 1, 256, 0, stream>>>(proj_bf, out_W, out_b, tgt, stats,
      NTILE_V, loss_acc, prog, 12);

  finalize_kernel<<<1, 1, 0, stream>>>(loss_acc, prog, biasE, biasD,
      enc_out, cat, proj_bf, stats, (float*)d_out);
}